// Round 13
// baseline (202.123 us; speedup 1.0000x reference)
//
#include <hip/hip_runtime.h>
#include <math.h>

#define BB 4
#define CC 256
#define OC 256
#define HH 64
#define WW2 64
#define HW 4096
#define UP_HW 16384
#define NOFF 27
#define EPSV 1e-5f
#define TPX 32

typedef _Float16 f16;
typedef f16 f16x2 __attribute__((ext_vector_type(2)));
typedef f16 f16x4 __attribute__((ext_vector_type(4)));
typedef f16 f16x8 __attribute__((ext_vector_type(8)));
typedef float f32x4 __attribute__((ext_vector_type(4)));
typedef float f32x16 __attribute__((ext_vector_type(16)));

// async global->LDS, 16B per lane; LDS dest = uniform base + lane*16
#define GLOAD16(GP, LP) __builtin_amdgcn_global_load_lds( \
    (const __attribute__((address_space(1))) void*)(GP),  \
    (__attribute__((address_space(3))) void*)(LP), 16, 0, 0)

// ---------------- fallback K1: offset/mask conv (VALU) ----------------
__global__ __launch_bounds__(256) void k_offset(
    const float* __restrict__ x, const float* __restrict__ w,
    const float* __restrict__ bias, float* __restrict__ om) {
  const int b = blockIdx.z;
  const int ocg = blockIdx.y * 3;
  const int row = threadIdx.x >> 6;
  const int h = blockIdx.x * 4 + row;
  const int col = threadIdx.x & 63;
  const float* xb = x + (size_t)b * CC * HW;
  float a0 = 0.f, a1 = 0.f, a2 = 0.f;
  for (int ic = 0; ic < CC; ++ic) {
    const float* xc = xb + ic * HW;
    float xm[3], xl[3], xr[3];
    #pragma unroll
    for (int dy = 0; dy < 3; ++dy) {
      int hy = h + dy - 1;
      float v = (hy >= 0 && hy < HH) ? xc[hy * WW2 + col] : 0.f;
      xm[dy] = v;
      float up = __shfl_up(v, 1, 64);
      float dn = __shfl_down(v, 1, 64);
      xl[dy] = (col == 0) ? 0.f : up;
      xr[dy] = (col == 63) ? 0.f : dn;
    }
    #pragma unroll
    for (int j = 0; j < 3; ++j) {
      const float* wp = w + ((size_t)(ocg + j) * CC + ic) * 9;
      float s = 0.f;
      #pragma unroll
      for (int dy = 0; dy < 3; ++dy) {
        s = fmaf(wp[dy * 3 + 0], xl[dy], s);
        s = fmaf(wp[dy * 3 + 1], xm[dy], s);
        s = fmaf(wp[dy * 3 + 2], xr[dy], s);
      }
      if (j == 0) a0 += s; else if (j == 1) a1 += s; else a2 += s;
    }
  }
  #pragma unroll
  for (int j = 0; j < 3; ++j) {
    int oc = ocg + j;
    float v = (j == 0 ? a0 : (j == 1 ? a1 : a2)) + bias[oc];
    if (oc >= 18) v = 1.f / (1.f + expf(-v));
    om[((size_t)(b * NOFF + oc)) * HW + h * WW2 + col] = v;
  }
}

// ---------------- fallback: VALU deformable conv ----------------
__global__ __launch_bounds__(256) void k_dcn(
    const float* __restrict__ x, const float* __restrict__ om,
    const float* __restrict__ wd, float* __restrict__ out) {
  __shared__ int s_idx[4][TPX * 9];
  __shared__ float s_bw[4][TPX * 9];
  __shared__ __align__(16) float s_v[2][TPX * 9];
  __shared__ __align__(16) float s_wd[2][9][256];
  const int b = blockIdx.y;
  const int p0 = blockIdx.x * TPX;
  const int h = p0 >> 6;
  const int tid = threadIdx.x;

  for (int e = tid; e < TPX * 9; e += 256) {
    int px = e & (TPX - 1);
    int k = e >> 5;
    int p = p0 + px;
    int wc = p & 63;
    float offx = om[((size_t)(b * NOFF + k)) * HW + p];
    float offy = om[((size_t)(b * NOFF + 9 + k)) * HW + p];
    float msk  = om[((size_t)(b * NOFF + 18 + k)) * HW + p];
    float sy = offy + (float)(k / 3 - 1) + (float)h;
    float sx = offx + (float)(k % 3 - 1) + (float)wc;
    float fy = floorf(sy), fx = floorf(sx);
    float ly = sy - fy, lx = sx - fx;
    int iy = (int)fy, ix = (int)fx;
    #pragma unroll
    for (int cnr = 0; cnr < 4; ++cnr) {
      int dy = cnr >> 1, dx = cnr & 1;
      int yy = iy + dy, xx = ix + dx;
      bool val = (yy >= 0) & (yy < HH) & (xx >= 0) & (xx < WW2);
      float wt = (dy ? ly : 1.f - ly) * (dx ? lx : 1.f - lx) * msk;
      s_idx[cnr][e] = val ? (yy * WW2 + xx) : 0;
      s_bw[cnr][e] = val ? wt : 0.f;
    }
  }
  __syncthreads();

  const int og = tid >> 3, pg = tid & 7;
  float acc[8][4] = {};
  const float* xb = x + (size_t)b * CC * HW;
  for (int ic = 0; ic < CC; ic += 2) {
    {
      const float* wp = wd + (size_t)tid * (CC * 9) + ic * 9;
      #pragma unroll
      for (int t = 0; t < 18; ++t)
        s_wd[t / 9][t % 9][tid] = wp[t];
    }
    #pragma unroll
    for (int t = 0; t < 3; ++t) {
      int e = tid + t * 256;
      if (e < 2 * TPX * 9) {
        int icc = (e >= TPX * 9);
        int r = e - icc * TPX * 9;
        const float* xc = xb + (ic + icc) * HW;
        float v = s_bw[0][r] * xc[s_idx[0][r]] + s_bw[1][r] * xc[s_idx[1][r]]
                + s_bw[2][r] * xc[s_idx[2][r]] + s_bw[3][r] * xc[s_idx[3][r]];
        s_v[icc][r] = v;
      }
    }
    __syncthreads();
    #pragma unroll
    for (int icc = 0; icc < 2; ++icc) {
      #pragma unroll
      for (int k = 0; k < 9; ++k) {
        float4 v4 = *(const float4*)&s_v[icc][k * TPX + pg * 4];
        float4 wa = *(const float4*)&s_wd[icc][k][og * 8];
        float4 wb = *(const float4*)&s_wd[icc][k][og * 8 + 4];
        float vi[4] = {v4.x, v4.y, v4.z, v4.w};
        float wj[8] = {wa.x, wa.y, wa.z, wa.w, wb.x, wb.y, wb.z, wb.w};
        #pragma unroll
        for (int j = 0; j < 8; ++j)
          #pragma unroll
          for (int i = 0; i < 4; ++i)
            acc[j][i] = fmaf(wj[j], vi[i], acc[j][i]);
      }
    }
    __syncthreads();
  }
  #pragma unroll
  for (int j = 0; j < 8; ++j) {
    int oc = og * 8 + j;
    float4 o = make_float4(acc[j][0], acc[j][1], acc[j][2], acc[j][3]);
    *(float4*)&out[((size_t)(b * OC + oc)) * HW + p0 + pg * 4] = o;
  }
}

// ---------------- BN batch stats (biased var), one block per channel (fallback) ----------------
__global__ __launch_bounds__(256) void k_stats(
    const float* __restrict__ d, int perB, float* __restrict__ mean,
    float* __restrict__ rinv) {
  const int c = blockIdx.x, tid = threadIdx.x;
  double s1 = 0.0, s2 = 0.0;
  const int n4 = perB >> 2;
  for (int b = 0; b < BB; ++b) {
    const float4* p = (const float4*)(d + ((size_t)(b * CC + c)) * perB);
    for (int i = tid; i < n4; i += 256) {
      float4 v = p[i];
      s1 += (double)v.x + (double)v.y + (double)v.z + (double)v.w;
      s2 += (double)v.x * v.x + (double)v.y * v.y + (double)v.z * v.z + (double)v.w * v.w;
    }
  }
  __shared__ double r1[256], r2[256];
  r1[tid] = s1; r2[tid] = s2;
  __syncthreads();
  for (int s = 128; s > 0; s >>= 1) {
    if (tid < s) { r1[tid] += r1[tid + s]; r2[tid] += r2[tid + s]; }
    __syncthreads();
  }
  if (tid == 0) {
    double n = (double)perB * BB;
    double m = r1[0] / n;
    double var = r2[0] / n - m * m;
    mean[c] = (float)m;
    rinv[c] = (float)(1.0 / sqrt(var + (double)EPSV));
  }
}

// ---------------- BN stats, 2-level: partials per (b,c), then finalize ----------------
__global__ __launch_bounds__(256) void k_stats_part(
    const float* __restrict__ d, int perB, double* __restrict__ part) {
  const int c = blockIdx.x & 255, b = blockIdx.x >> 8;
  const int tid = threadIdx.x;
  double s1 = 0.0, s2 = 0.0;
  const float4* p = (const float4*)(d + ((size_t)(b * CC + c)) * perB);
  const int n4 = perB >> 2;
  for (int i = tid; i < n4; i += 256) {
    float4 v = p[i];
    s1 += (double)v.x + (double)v.y + (double)v.z + (double)v.w;
    s2 += (double)v.x * v.x + (double)v.y * v.y + (double)v.z * v.z + (double)v.w * v.w;
  }
  __shared__ double r1[256], r2[256];
  r1[tid] = s1; r2[tid] = s2;
  __syncthreads();
  for (int s = 128; s > 0; s >>= 1) {
    if (tid < s) { r1[tid] += r1[tid + s]; r2[tid] += r2[tid + s]; }
    __syncthreads();
  }
  if (tid == 0) {
    part[blockIdx.x] = r1[0];
    part[1024 + blockIdx.x] = r2[0];
  }
}

__global__ __launch_bounds__(256) void k_stats_fin(
    const double* __restrict__ part, int perB, float* __restrict__ mean,
    float* __restrict__ rinv) {
  const int c = threadIdx.x;  // 1 block x 256 threads
  double s1 = 0.0, s2 = 0.0;
  #pragma unroll
  for (int b = 0; b < BB; ++b) {
    s1 += part[b * 256 + c];
    s2 += part[1024 + b * 256 + c];
  }
  double n = (double)perB * BB;
  double m = s1 / n;
  double var = s2 / n - m * m;
  mean[c] = (float)m;
  rinv[c] = (float)(1.0 / sqrt(var + (double)EPSV));
}

// ---------------- BN apply + ReLU, in place ----------------
__global__ __launch_bounds__(256) void k_bnrelu(
    float* __restrict__ d, const float* __restrict__ mean,
    const float* __restrict__ rinv, const float* __restrict__ g,
    const float* __restrict__ be, int perB, int total4) {
  int stride = gridDim.x * blockDim.x;
  for (int i4 = blockIdx.x * blockDim.x + threadIdx.x; i4 < total4; i4 += stride) {
    int c = (int)((((long long)i4 * 4) / perB) & 255);
    float sc = rinv[c] * g[c];
    float shv = fmaf(-mean[c], sc, be[c]);
    float4 v = ((float4*)d)[i4];
    v.x = fmaxf(fmaf(v.x, sc, shv), 0.f);
    v.y = fmaxf(fmaf(v.y, sc, shv), 0.f);
    v.z = fmaxf(fmaf(v.z, sc, shv), 0.f);
    v.w = fmaxf(fmaf(v.w, sc, shv), 0.f);
    ((float4*)d)[i4] = v;
  }
}

// halo zeroing helper: block (h, cg, wg, b) zeroes its 32-ch slice of the 1-px halo
__device__ __forceinline__ void halo_zero(f16* __restrict__ dst, int b, int h,
                                          int cg, int wg, int t) {
  const f16x8 z = {};
  // col halo: cell (h+1, 0) for wg==0, (h+1, 65) for wg==1
  if (t < 4) {
    f16* p = dst + (((size_t)(b * 66 + h + 1) * 66) + (wg ? 65 : 0)) * 256 + cg * 32 + t * 8;
    *(f16x8*)p = z;
  }
  if (h == 0 || h == 63) {
    int hr = (h == 0) ? 0 : 65;
    // row halo: cols wg*32+1 .. wg*32+32 (32 cols x 32 ch)
    if (t < 128) {
      int col = wg * 32 + 1 + (t >> 2);
      f16* p = dst + (((size_t)(b * 66 + hr) * 66) + col) * 256 + cg * 32 + (t & 3) * 8;
      *(f16x8*)p = z;
    }
    // corners: (hr, 0) for wg==0, (hr, 65) for wg==1
    if (t >= 128 && t < 132) {
      f16* p = dst + (((size_t)(b * 66 + hr) * 66) + (wg ? 65 : 0)) * 256 + cg * 32 + (t - 128) * 8;
      *(f16x8*)p = z;
    }
  }
}

// ---------------- NCHW f32 -> padded NHWC f16 dst[b][66][66][256], halo zeroed ----------------
__global__ __launch_bounds__(256) void k_totile(const float* __restrict__ y,
                                                f16* __restrict__ yTp) {
  __shared__ float S[32][33];
  const int h = blockIdx.x;
  const int cg = blockIdx.y >> 1;
  const int wg = blockIdx.y & 1;
  const int b = blockIdx.z;
  const int t = threadIdx.x;
  {
    int ci = t >> 3, q = t & 7;
    const float* src = y + (((size_t)(b * 256 + cg * 32 + ci) * 64 + h) * 64 + wg * 32 + q * 4);
    float4 v = *(const float4*)src;
    S[ci][q * 4 + 0] = v.x; S[ci][q * 4 + 1] = v.y;
    S[ci][q * 4 + 2] = v.z; S[ci][q * 4 + 3] = v.w;
  }
  halo_zero(yTp, b, h, cg, wg, t);
  __syncthreads();
  {
    int w = t >> 3, c2 = t & 7;
    f16x4 pv;
    pv[0] = (f16)S[c2 * 4 + 0][w];
    pv[1] = (f16)S[c2 * 4 + 1][w];
    pv[2] = (f16)S[c2 * 4 + 2][w];
    pv[3] = (f16)S[c2 * 4 + 3][w];
    f16* dst = yTp + (((size_t)(b * 66 + h + 1) * 66 + (wg * 32 + w + 1)) * 256 + cg * 32 + c2 * 4);
    *(f16x4*)dst = pv;
  }
}

// ---------------- fused: BN+ReLU (in place on y) + padded NHWC f16 tile, halo zeroed --------
__global__ __launch_bounds__(256) void k_totile_bn(
    const float* __restrict__ mean, const float* __restrict__ rinv,
    const float* __restrict__ g, const float* __restrict__ be,
    float* __restrict__ y, f16* __restrict__ yTp) {
  __shared__ float S[32][33];
  const int h = blockIdx.x;
  const int cg = blockIdx.y >> 1;
  const int wg = blockIdx.y & 1;
  const int b = blockIdx.z;
  const int t = threadIdx.x;
  {
    int ci = t >> 3, q = t & 7;
    int c = cg * 32 + ci;
    float sc = rinv[c] * g[c];
    float sh = fmaf(-mean[c], sc, be[c]);
    float* src = y + (((size_t)(b * 256 + c) * 64 + h) * 64 + wg * 32 + q * 4);
    float4 v = *(const float4*)src;
    v.x = fmaxf(fmaf(v.x, sc, sh), 0.f);
    v.y = fmaxf(fmaf(v.y, sc, sh), 0.f);
    v.z = fmaxf(fmaf(v.z, sc, sh), 0.f);
    v.w = fmaxf(fmaf(v.w, sc, sh), 0.f);
    *(float4*)src = v;
    S[ci][q * 4 + 0] = v.x; S[ci][q * 4 + 1] = v.y;
    S[ci][q * 4 + 2] = v.z; S[ci][q * 4 + 3] = v.w;
  }
  halo_zero(yTp, b, h, cg, wg, t);
  __syncthreads();
  {
    int w = t >> 3, c2 = t & 7;
    f16x4 pv;
    pv[0] = (f16)S[c2 * 4 + 0][w];
    pv[1] = (f16)S[c2 * 4 + 1][w];
    pv[2] = (f16)S[c2 * 4 + 2][w];
    pv[3] = (f16)S[c2 * 4 + 3][w];
    f16* dst = yTp + (((size_t)(b * 66 + h + 1) * 66 + (wg * 32 + w + 1)) * 256 + cg * 32 + c2 * 4);
    *(f16x4*)dst = pv;
  }
}

// ---------------- merged weight prep: wprep(128) | wodprep(32) | wdprep(256) ----------------
__global__ __launch_bounds__(256) void k_prep(
    const float* __restrict__ wu, f16* __restrict__ Wt,
    const float* __restrict__ wo, f16* __restrict__ Wod,
    const float* __restrict__ wd, f16* __restrict__ Wd) {
  const int bx = blockIdx.x;
  if (bx < 128) {
    const int ic = bx * 2;
    const int oc = threadIdx.x;
    float a[16], c[16];
    const float* p0 = wu + ((size_t)(ic * 256 + oc)) * 16;
    const float* p1 = wu + ((size_t)((ic + 1) * 256 + oc)) * 16;
    #pragma unroll
    for (int k = 0; k < 4; ++k) {
      float4 v = *(const float4*)(p0 + k * 4);
      a[k * 4 + 0] = v.x; a[k * 4 + 1] = v.y; a[k * 4 + 2] = v.z; a[k * 4 + 3] = v.w;
      float4 w2 = *(const float4*)(p1 + k * 4);
      c[k * 4 + 0] = w2.x; c[k * 4 + 1] = w2.y; c[k * 4 + 2] = w2.z; c[k * 4 + 3] = w2.w;
    }
    #pragma unroll
    for (int kh = 0; kh < 4; ++kh)
      #pragma unroll
      for (int kw = 0; kw < 4; ++kw) {
        int po = (kh & 1) ^ 1, dh = kh >> 1;
        int qo = (kw & 1) ^ 1, dw = kw >> 1;
        int combo = (po * 2 + qo) * 4 + (dh * 2 + dw);
        f16x2 pv;
        pv[0] = (f16)a[kh * 4 + kw];
        pv[1] = (f16)c[kh * 4 + kw];
        *(f16x2*)&Wt[((size_t)(combo * 256 + oc)) * 256 + ic] = pv;
      }
  } else if (bx < 160) {
    const int oc = bx - 128;
    const int ic = threadIdx.x;
    const int icg = ic >> 3, e = ic & 7;
    #pragma unroll
    for (int tap = 0; tap < 9; ++tap) {
      f16 v = (f16)0.f;
      if (oc < NOFF) v = (f16)wo[((size_t)oc * 256 + ic) * 9 + tap];
      Wod[(((size_t)(tap * 32 + icg)) * 32 + oc) * 8 + e] = v;
    }
  } else {
    const int oc = bx - 160;
    const int ic = threadIdx.x;
    const float* src = wd + ((size_t)oc * 256 + ic) * 9;
    f16* dst = Wd + (((size_t)(ic >> 3) * 256 + oc)) * 8 + (ic & 7);
    #pragma unroll
    for (int tap = 0; tap < 9; ++tap)
      dst[(size_t)tap * 32 * 256 * 8] = (f16)src[tap];
  }
}

// standalone wprep for the fallback path
__global__ __launch_bounds__(256) void k_wprep(const float* __restrict__ wu,
                                               f16* __restrict__ Wt) {
  const int ic = blockIdx.x * 2;
  const int oc = threadIdx.x;
  float a[16], c[16];
  const float* p0 = wu + ((size_t)(ic * 256 + oc)) * 16;
  const float* p1 = wu + ((size_t)((ic + 1) * 256 + oc)) * 16;
  #pragma unroll
  for (int k = 0; k < 4; ++k) {
    float4 v = *(const float4*)(p0 + k * 4);
    a[k * 4 + 0] = v.x; a[k * 4 + 1] = v.y; a[k * 4 + 2] = v.z; a[k * 4 + 3] = v.w;
    float4 w2 = *(const float4*)(p1 + k * 4);
    c[k * 4 + 0] = w2.x; c[k * 4 + 1] = w2.y; c[k * 4 + 2] = w2.z; c[k * 4 + 3] = w2.w;
  }
  #pragma unroll
  for (int kh = 0; kh < 4; ++kh)
    #pragma unroll
    for (int kw = 0; kw < 4; ++kw) {
      int po = (kh & 1) ^ 1, dh = kh >> 1;
      int qo = (kw & 1) ^ 1, dw = kw >> 1;
      int combo = (po * 2 + qo) * 4 + (dh * 2 + dw);
      f16x2 pv;
      pv[0] = (f16)a[kh * 4 + kw];
      pv[1] = (f16)c[kh * 4 + kw];
      *(f16x2*)&Wt[((size_t)(combo * 256 + oc)) * 256 + ic] = pv;
    }
}

// ---------------- offset conv as MFMA GEMM, one image row per block ----------------
__global__ __launch_bounds__(256) void k_off_mfma(
    const f16* __restrict__ xtp, const f16* __restrict__ Wod,
    const float* __restrict__ bias, float* __restrict__ om) {
  __shared__ __align__(16) f16 Alds[9 * 4 * 32 * 8];  // 18 KB, slot = idx
  __shared__ __align__(16) f16 Blds[3 * 4 * 66 * 8];  // 12.4 KB, slot = idx
  const int b = blockIdx.y;
  const int r = blockIdx.x;            // image row 0..63
  const int tid = threadIdx.x;
  const int lane = tid & 63, wave = tid >> 6;
  const int l15 = lane & 15, l4 = lane >> 4;
  const int wbase = tid & 192;
  f32x4 acc[2] = {};
  const size_t xbase = ((size_t)b * 66 + r) * 66;  // padded rows r..r+2

  for (int ic0 = 0; ic0 < 256; ic0 += 32) {
    __syncthreads();
    #pragma unroll
    for (int i = 0; i < 5; ++i) {
      int idx = i * 256 + tid;
      if (idx < 1152) {
        int tap = idx >> 7, g = (idx >> 5) & 3, oc = idx & 31;
        const f16* gp = Wod + (((size_t)(tap * 32 + (ic0 >> 3) + g)) * 32 + oc) * 8;
        GLOAD16(gp, Alds + (size_t)(i * 256 + wbase) * 8);
      }
    }
    #pragma unroll
    for (int i = 0; i < 4; ++i) {
      int idx = i * 256 + tid;
      if (idx < 792) {
        int rp4g = idx / 66, c = idx - rp4g * 66;
        int rp = rp4g >> 2, g = rp4g & 3;
        const f16* gp = xtp + ((xbase + rp * 66 + c) * 256 + ic0 + g * 8);
        GLOAD16(gp, Blds + (size_t)(i * 256 + wbase) * 8);
      }
    }
    __syncthreads();
    #pragma unroll
    for (int tap = 0; tap < 9; ++tap) {
      const int ky = tap / 3, kx = tap % 3;
      f16x8 af[2];
      #pragma unroll
      for (int fi = 0; fi < 2; ++fi)
        af[fi] = *(const f16x8*)&Alds[((tap * 4 + l4) * 32 + fi * 16 + l15) * 8];
      f16x8 bf = *(const f16x8*)&Blds[((ky * 4 + l4) * 66 + wave * 16 + l15 + kx) * 8];
      #pragma unroll
      for (int fi = 0; fi < 2; ++fi)
        acc[fi] = __builtin_amdgcn_mfma_f32_16x16x32_f16(af[fi], bf, acc[fi], 0, 0, 0);
    }
  }
  #pragma unroll
  for (int fi = 0; fi < 2; ++fi) {
    #pragma unroll
    for (int r4 = 0; r4 < 4; ++r4) {
      int oc = fi * 16 + l4 * 4 + r4;
      if (oc < NOFF) {
        float v = acc[fi][r4] + bias[oc];
        if (oc >= 18) v = 1.f / (1.f + expf(-v));
        om[((size_t)(b * NOFF + oc)) * HW + r * 64 + wave * 16 + l15] = v;
      }
    }
  }
}

// ---------------- bilinear+mask sampling from padded xtp: V[vb][tap][icg][px][8] ----------------
__global__ __launch_bounds__(256) void k_sample(
    const f16* __restrict__ xtp, const float* __restrict__ om,
    f16* __restrict__ V, int b0) {
  const int tap = blockIdx.y;
  const int vb = blockIdx.z;
  const int b = b0 + vb;
  const int p = blockIdx.x * 64 + (threadIdx.x & 63);
  const int icg0 = threadIdx.x >> 6;
  const int h = p >> 6, w = p & 63;
  const float offx = om[((size_t)(b * NOFF + tap)) * HW + p];
  const float offy = om[((size_t)(b * NOFF + 9 + tap)) * HW + p];
  const float msk  = om[((size_t)(b * NOFF + 18 + tap)) * HW + p];
  float sy = offy + (float)(tap / 3 - 1) + (float)h;
  float sx = offx + (float)(tap % 3 - 1) + (float)w;
  float fy = floorf(sy), fx = floorf(sx);
  float ly = sy - fy, lx = sx - fx;
  int iy = (int)fy, ix = (int)fx;
  int idx[4];
  float wg[4];
  #pragma unroll
  for (int cnr = 0; cnr < 4; ++cnr) {
    int dy = cnr >> 1, dx = cnr & 1;
    int yy = iy + dy, xx = ix + dx;
    bool val = (yy >= 0) & (yy < HH) & (xx >= 0) & (xx < WW2);
    float wt = (dy ? ly : 1.f - ly) * (dx ? lx : 1.f - lx) * msk;
    idx[cnr] = val ? ((yy + 1) * 66 + (xx + 1)) : 0;
    wg[cnr] = val ? wt : 0.f;
  }
  const f16* xb = xtp + (size_t)b * 66 * 66 * 256;
  f16* vout = V + (((size_t)(vb * 9 + tap) * 32) * HW + p) * 8;
  #pragma unroll
  for (int it = 0; it < 8; ++it) {
    int icg = icg0 + it * 4;
    f16x8 c0 = *(const f16x8*)(xb + (size_t)idx[0] * 256 + icg * 8);
    f16x8 c1 = *(const f16x8*)(xb + (size_t)idx[1] * 256 + icg * 8);
    f16x8 c2 = *(const f16x8*)(xb + (size_t)idx[2] * 256 + icg * 8);
    f16x8 c3 = *(const f16x8*)(xb + (size_t)idx[3] * 256 + icg * 8);
    f16x8 r;
    #pragma unroll
    for (int e = 0; e < 8; ++e) {
      float s = wg[0] * (float)c0[e];
      s = fmaf(wg[1], (float)c1[e], s);
      s = fmaf(wg[2], (float)c2[e], s);
      s = fmaf(wg[3], (float)c3[e], s);
      r[e] = (f16)s;
    }
    *(f16x8*)(vout + (size_t)icg * HW * 8) = r;
  }
}

// ---------------- DCN GEMM via MFMA, 128oc x 64px tile, BK=64, global_load_lds ----------------
// grid (64 pxtile, 2 octile, nb), block 256 = 4 waves (2m x 2n; wave = 64oc x 32px)
__global__ __launch_bounds__(256) void k_dcn_mfma(
    const f16* __restrict__ V, const f16* __restrict__ Wd,
    float* __restrict__ out, int b0) {
  __shared__ __align__(16) f16 Alds[8 * 128 * 8];   // 16 KB, slot = idx (g*128+oc)
  __shared__ __align__(16) f16 Blds[8 * 64 * 8];    // 8 KB,  slot = idx (g*64+px)
  const int vb = blockIdx.z;
  const int b = b0 + vb;
  const int oc0 = blockIdx.y * 128;
  const int px0 = blockIdx.x * 64;
  const int tid = threadIdx.x;
  const int lane = tid & 63;
  const int wave = tid >> 6;
  const int wm = wave >> 1, wn = wave & 1;
  const int l15 = lane & 15, l4 = lane >> 4;
  const int wbase = tid & 192;  // wave*64
  f32x4 acc[4][2] = {};
  const size_t vrow = (size_t)(vb * 9) * 32;

  for (int tap = 0; tap < 9; ++tap) {
    for (int kk = 0; kk < 4; ++kk) {  // 64 ic per step
      __syncthreads();  // previous compute done before DMA overwrites LDS
      #pragma unroll
      for (int i = 0; i < 4; ++i) {   // A: 1024 chunks
        int idx = i * 256 + tid;
        int g = idx >> 7, q = idx & 127;
        const f16* gpA = Wd + (((size_t)((tap * 32 + kk * 8 + g) * 256) + oc0 + q)) * 8;
        GLOAD16(gpA, Alds + (size_t)(i * 256 + wbase) * 8);
      }
      #pragma unroll
      for (int i = 0; i < 2; ++i) {   // B: 512 chunks
        int idx = i * 256 + tid;
        int g = idx >> 6, q = idx & 63;
        const f16* gpB = V + ((vrow + tap * 32 + kk * 8 + g) * HW + px0 + q) * 8;
        GLOAD16(gpB, Blds + (size_t)(i * 256 + wbase) * 8);
      }
      __syncthreads();  // vmcnt(0) drain -> staged data visible
      #pragma unroll
      for (int half = 0; half < 2; ++half) {
        f16x8 af[4], bf[2];
        #pragma unroll
        for (int fi = 0; fi < 4; ++fi)
          af[fi] = *(const f16x8*)&Alds[(((half * 4 + l4) * 128) + wm * 64 + fi * 16 + l15) * 8];
        #pragma unroll
        for (int ni = 0; ni < 2; ++ni)
          bf[ni] = *(const f16x8*)&Blds[(((half * 4 + l4) * 64) + wn * 32 + ni * 16 + l15) * 8];
        #pragma unroll
        for (int fi = 0; fi < 4; ++fi)
          #pragma unroll
          for (int ni = 0; ni < 2; ++ni)
            acc[fi][ni] = __builtin_amdgcn_mfma_f32_16x16x32_f16(af[fi], bf[ni], acc[fi][ni], 0, 0, 0);
      }
    }
  }
  #pragma unroll
  for (int fi = 0; fi < 4; ++fi) {
    int oc = oc0 + wm * 64 + fi * 16 + l4 * 4;
    #pragma unroll
    for (int ni = 0; ni < 2; ++ni) {
      int px = px0 + wn * 32 + ni * 16 + l15;
      float* op = out + ((size_t)(b * OC + oc)) * HW + px;
      #pragma unroll
      for (int r = 0; r < 4; ++r)
        op[(size_t)r * HW] = acc[fi][ni][r];
    }
  }
}

// ---------------- ConvTranspose2d: 4 subpixel GEMMs, 128oc x 256px, 32x32x16 MFMA ----------
// grid (16 sh-quads, 8 = sub*2+octile, 4 b), block 256 = 4 waves (2m x 2n, wave 64oc x 128px)
__global__ __launch_bounds__(256) void k_up_mfma(
    const f16* __restrict__ yTp, const f16* __restrict__ Wt,
    float* __restrict__ out) {
  __shared__ __align__(16) f16 Alds[4 * 4 * 128 * 8];  // 32 KB, slot (tap*4+g)*128+oc
  __shared__ __align__(16) f16 Blds[5 * 4 * 66 * 8];   // 20.6 KB, slot (rp*4+g)*66+c
  const int b = blockIdx.z;
  const int sub = blockIdx.y >> 1;
  const int po = sub >> 1, qo = sub & 1;
  const int oc0 = (blockIdx.y & 1) * 128;
  const int sh0 = blockIdx.x * 4;
  const int tid = threadIdx.x;
  const int lane = tid & 63, wave = tid >> 6;
  const int wm = wave >> 1, wn = wave & 1;
  const int l31 = lane & 31, l5 = lane >> 5;
  const int wbase = tid & 192;  // wave*64
  f32x16 acc[2][4] = {};
  const size_t yrow = ((size_t)b * 66 + (sh0 + po)) * 66;

  for (int ic0 = 0; ic0 < 256; ic0 += 32) {
    __syncthreads();  // previous compute done before DMA overwrites LDS
    // stage A: 2048 chunks (4 taps x 4 g x 128 oc)
    #pragma unroll
    for (int i = 0; i < 8; ++i) {
      int idx = i * 256 + tid;
      int tap = idx >> 9, g = (idx >> 7) & 3, oc = idx & 127;
      const f16* gp = Wt + (((size_t)((sub * 4 + tap) * 256 + oc0 + oc)) * 256 + ic0 + g * 8);
      GLOAD16(gp, Alds + (size_t)(i * 256 + wbase) * 8);
    }
    // stage B: 1320 chunks (5 rows x 4 g x 66 cols)
    #pragma unroll
    for (int i = 0; i < 6; ++i) {
      int idx = i * 256 + tid;
      if (idx < 1320) {
        int rp4g = idx / 66, c = idx - rp4g * 66;
        int rp = rp4g >> 2, g = rp4g & 3;
        const f16* gp = yTp + ((yrow + rp * 66 + c) * 256 + ic0 + g * 8);
        GLOAD16(gp, Blds + (size_t)(i * 256 + wbase) * 8);
      }
    }
    __syncthreads();  // vmcnt(0) drain -> staged data visible
    #pragma unroll
    for (int tap = 0; tap < 4; ++tap) {
      const int dh = tap >> 1, dw = tap & 1;
      #pragma unroll
      for (int kk2 = 0; kk2 < 2; ++kk2) {   // K=16 halves of the 32-ic step
        f16x8 af[2];
        #pragma unroll
        for (int fi = 0; fi < 2; ++fi)      // A: m=l31 (oc), k=8*l5+j
          af[fi] = *(const f16x8*)&Alds[((tap * 4 + kk2 * 2 + l5) * 128 + wm * 64 + fi * 32 + l31) * 8];
        #pragma unroll
        for (int ni = 0; ni < 4; ++ni) {    // B: n=l31 (px), k=8*l5+j
          int prow = wn * 2 + (ni >> 1);
          int cp = (ni & 1) * 32 + l31 + qo - dw + 1;
          f16x8 bf = *(const f16x8*)&Blds[(((prow + 1 - dh) * 4 + kk2 * 2 + l5) * 66 + cp) * 8];
          #pragma unroll
          for (int fi = 0; fi < 2; ++fi)
            acc[fi][ni] = __builtin_amdgcn_mfma_f32_32x32x16_f16(af[fi], bf, acc[fi][ni], 0, 0, 0);
        }
      }
    }
  }
  // D layout (m74/m101): col = lane&31 (px), row = (reg&3)+8*(reg>>2)+4*(lane>>5) (oc)
  #pragma unroll
  for (int fi = 0; fi < 2; ++fi) {
    #pragma unroll
    for (int ni = 0; ni < 4; ++ni) {
      int pxb = wn * 128 + ni * 32;
      int sh = sh0 + (pxb >> 6);
      int ow = 2 * ((pxb & 63) + l31) + qo;
      #pragma unroll
      for (int r = 0; r < 16; ++r) {
        int oc = oc0 + wm * 64 + fi * 32 + (r & 3) + 8 * (r >> 2) + 4 * l5;
        out[((size_t)(b * 256 + oc)) * UP_HW + (2 * sh + po) * 128 + ow] = acc[fi][ni][r];
      }
    }
  }
}

extern "C" void kernel_launch(void* const* d_in, const int* in_sizes, int n_in,
                              void* d_out, int out_size, void* d_ws, size_t ws_size,
                              hipStream_t stream) {
  const float* x      = (const float*)d_in[0];
  const float* w_off  = (const float*)d_in[1];
  const float* b_off  = (const float*)d_in[2];
  const float* w_dcn  = (const float*)d_in[3];
  const float* gamma1 = (const float*)d_in[4];
  const float* beta1  = (const float*)d_in[5];
  const float* w_up   = (const float*)d_in[6];
  const float* gamma2 = (const float*)d_in[7];
  const float* beta2  = (const float*)d_in[8];

  float* out1 = (float*)d_out;                   // y      [4,256,64,64]
  float* out2 = out1 + (size_t)BB * OC * HW;     // y_up   [4,256,128,128]

  char* wsb = (char*)d_ws;
  float* om    = (float*)wsb;                               // 1,769,472
  float* mean1 = (float*)(wsb + 1769472);
  float* rinv1 = mean1 + 256;
  float* mean2 = rinv1 + 256;
  float* rinv2 = mean2 + 256;
  f16* yTp = (f16*)(wsb + 1773568);                         // 8,921,088
  f16* Wt  = (f16*)(wsb + 10694656);                        // 2,097,152
  f16* xtp = (f16*)(wsb + 12791808);                        // 8,921,088
  f16* Wd  = (f16*)(wsb + 21712896);                        // 1,179,648
  f16* Wod = (f16*)(wsb + 22892544);                        // 147,456
  f16* V   = (f16*)(wsb + 23040000);                        // nb * 18,874,368
  const size_t FIXED_END = 23040000;
  const size_t VB_BYTES = 18874368;

  int nb = 0;
  if (ws_size >= FIXED_END + 4 * VB_BYTES) nb = 4;
  else if (ws_size >= FIXED_END + 2 * VB_BYTES) nb = 2;
  else if (ws_size >= FIXED_END + VB_BYTES) nb = 1;

  if (nb > 0) {
    double* partd = (double*)V;  // V space reused as 16 KB stats-partials scratch
    hipLaunchKernelGGL(k_prep, dim3(416), dim3(256), 0, stream, w_up, Wt, w_off, Wod, w_dcn, Wd);
    hipLaunchKernelGGL(k_totile, dim3(64, 16, BB), dim3(256), 0, stream, x, xtp);
    hipLaunchKernelGGL(k_off_mfma, dim3(64, BB), dim3(256), 0, stream, xtp, Wod, b_off, om);
    for (int b0 = 0; b0 < BB; b0 += nb) {
      hipLaunchKernelGGL(k_sample, dim3(64, 9, nb), dim3(256), 0, stream, xtp, om, V, b0);
      hipLaunchKernelGGL(k_dcn_mfma, dim3(64, 2, nb), dim3(256), 0, stream, V, Wd, out1, b0);
    }
    hipLaunchKernelGGL(k_stats_part, dim3(1024), dim3(256), 0, stream, out1, HW, partd);
    hipLaunchKernelGGL(k_stats_fin, dim3(1), dim3(256), 0, stream, partd, HW, mean1, rinv1);
    hipLaunchKernelGGL(k_totile_bn, dim3(64, 16, BB), dim3(256), 0, stream,
                       mean1, rinv1, gamma1, beta1, out1, yTp);
    hipLaunchKernelGGL(k_up_mfma, dim3(16, 8, BB), dim3(256), 0, stream, yTp, Wt, out2);
    hipLaunchKernelGGL(k_stats_part, dim3(1024), dim3(256), 0, stream, out2, UP_HW, partd);
    hipLaunchKernelGGL(k_stats_fin, dim3(1), dim3(256), 0, stream, partd, UP_HW, mean2, rinv2);
  } else {
    hipLaunchKernelGGL(k_wprep, dim3(128), dim3(256), 0, stream, w_up, Wt);
    hipLaunchKernelGGL(k_offset, dim3(16, 9, BB), dim3(256), 0, stream, x, w_off, b_off, om);
    hipLaunchKernelGGL(k_dcn, dim3(HW / TPX, BB), dim3(256), 0, stream, x, om, w_dcn, out1);
    hipLaunchKernelGGL(k_stats, dim3(256), dim3(256), 0, stream, out1, HW, mean1, rinv1);
    hipLaunchKernelGGL(k_bnrelu, dim3(2048), dim3(256), 0, stream, out1, mean1, rinv1,
                       gamma1, beta1, HW, (BB * OC * HW) / 4);
    hipLaunchKernelGGL(k_totile, dim3(64, 16, BB), dim3(256), 0, stream, out1, yTp);
    hipLaunchKernelGGL(k_up_mfma, dim3(16, 8, BB), dim3(256), 0, stream, yTp, Wt, out2);
    hipLaunchKernelGGL(k_stats, dim3(256), dim3(256), 0, stream, out2, UP_HW, mean2, rinv2);
  }

  hipLaunchKernelGGL(k_bnrelu, dim3(2048), dim3(256), 0, stream, out2, mean2, rinv2,
                     gamma2, beta2, UP_HW, (BB * OC * UP_HW) / 4);
}

// Round 14
// 196.089 us; speedup vs baseline: 1.0308x; 1.0308x over previous
//
#include <hip/hip_runtime.h>
#include <math.h>

#define BB 4
#define CC 256
#define OC 256
#define HH 64
#define WW2 64
#define HW 4096
#define UP_HW 16384
#define NOFF 27
#define EPSV 1e-5f
#define TPX 32

typedef _Float16 f16;
typedef f16 f16x2 __attribute__((ext_vector_type(2)));
typedef f16 f16x4 __attribute__((ext_vector_type(4)));
typedef f16 f16x8 __attribute__((ext_vector_type(8)));
typedef float f32x4 __attribute__((ext_vector_type(4)));

// async global->LDS, 16B per lane; LDS dest = uniform base + lane*16
#define GLOAD16(GP, LP) __builtin_amdgcn_global_load_lds( \
    (const __attribute__((address_space(1))) void*)(GP),  \
    (__attribute__((address_space(3))) void*)(LP), 16, 0, 0)

// ---------------- fallback K1: offset/mask conv (VALU) ----------------
__global__ __launch_bounds__(256) void k_offset(
    const float* __restrict__ x, const float* __restrict__ w,
    const float* __restrict__ bias, float* __restrict__ om) {
  const int b = blockIdx.z;
  const int ocg = blockIdx.y * 3;
  const int row = threadIdx.x >> 6;
  const int h = blockIdx.x * 4 + row;
  const int col = threadIdx.x & 63;
  const float* xb = x + (size_t)b * CC * HW;
  float a0 = 0.f, a1 = 0.f, a2 = 0.f;
  for (int ic = 0; ic < CC; ++ic) {
    const float* xc = xb + ic * HW;
    float xm[3], xl[3], xr[3];
    #pragma unroll
    for (int dy = 0; dy < 3; ++dy) {
      int hy = h + dy - 1;
      float v = (hy >= 0 && hy < HH) ? xc[hy * WW2 + col] : 0.f;
      xm[dy] = v;
      float up = __shfl_up(v, 1, 64);
      float dn = __shfl_down(v, 1, 64);
      xl[dy] = (col == 0) ? 0.f : up;
      xr[dy] = (col == 63) ? 0.f : dn;
    }
    #pragma unroll
    for (int j = 0; j < 3; ++j) {
      const float* wp = w + ((size_t)(ocg + j) * CC + ic) * 9;
      float s = 0.f;
      #pragma unroll
      for (int dy = 0; dy < 3; ++dy) {
        s = fmaf(wp[dy * 3 + 0], xl[dy], s);
        s = fmaf(wp[dy * 3 + 1], xm[dy], s);
        s = fmaf(wp[dy * 3 + 2], xr[dy], s);
      }
      if (j == 0) a0 += s; else if (j == 1) a1 += s; else a2 += s;
    }
  }
  #pragma unroll
  for (int j = 0; j < 3; ++j) {
    int oc = ocg + j;
    float v = (j == 0 ? a0 : (j == 1 ? a1 : a2)) + bias[oc];
    if (oc >= 18) v = 1.f / (1.f + expf(-v));
    om[((size_t)(b * NOFF + oc)) * HW + h * WW2 + col] = v;
  }
}

// ---------------- fallback: VALU deformable conv ----------------
__global__ __launch_bounds__(256) void k_dcn(
    const float* __restrict__ x, const float* __restrict__ om,
    const float* __restrict__ wd, float* __restrict__ out) {
  __shared__ int s_idx[4][TPX * 9];
  __shared__ float s_bw[4][TPX * 9];
  __shared__ __align__(16) float s_v[2][TPX * 9];
  __shared__ __align__(16) float s_wd[2][9][256];
  const int b = blockIdx.y;
  const int p0 = blockIdx.x * TPX;
  const int h = p0 >> 6;
  const int tid = threadIdx.x;

  for (int e = tid; e < TPX * 9; e += 256) {
    int px = e & (TPX - 1);
    int k = e >> 5;
    int p = p0 + px;
    int wc = p & 63;
    float offx = om[((size_t)(b * NOFF + k)) * HW + p];
    float offy = om[((size_t)(b * NOFF + 9 + k)) * HW + p];
    float msk  = om[((size_t)(b * NOFF + 18 + k)) * HW + p];
    float sy = offy + (float)(k / 3 - 1) + (float)h;
    float sx = offx + (float)(k % 3 - 1) + (float)wc;
    float fy = floorf(sy), fx = floorf(sx);
    float ly = sy - fy, lx = sx - fx;
    int iy = (int)fy, ix = (int)fx;
    #pragma unroll
    for (int cnr = 0; cnr < 4; ++cnr) {
      int dy = cnr >> 1, dx = cnr & 1;
      int yy = iy + dy, xx = ix + dx;
      bool val = (yy >= 0) & (yy < HH) & (xx >= 0) & (xx < WW2);
      float wt = (dy ? ly : 1.f - ly) * (dx ? lx : 1.f - lx) * msk;
      s_idx[cnr][e] = val ? (yy * WW2 + xx) : 0;
      s_bw[cnr][e] = val ? wt : 0.f;
    }
  }
  __syncthreads();

  const int og = tid >> 3, pg = tid & 7;
  float acc[8][4] = {};
  const float* xb = x + (size_t)b * CC * HW;
  for (int ic = 0; ic < CC; ic += 2) {
    {
      const float* wp = wd + (size_t)tid * (CC * 9) + ic * 9;
      #pragma unroll
      for (int t = 0; t < 18; ++t)
        s_wd[t / 9][t % 9][tid] = wp[t];
    }
    #pragma unroll
    for (int t = 0; t < 3; ++t) {
      int e = tid + t * 256;
      if (e < 2 * TPX * 9) {
        int icc = (e >= TPX * 9);
        int r = e - icc * TPX * 9;
        const float* xc = xb + (ic + icc) * HW;
        float v = s_bw[0][r] * xc[s_idx[0][r]] + s_bw[1][r] * xc[s_idx[1][r]]
                + s_bw[2][r] * xc[s_idx[2][r]] + s_bw[3][r] * xc[s_idx[3][r]];
        s_v[icc][r] = v;
      }
    }
    __syncthreads();
    #pragma unroll
    for (int icc = 0; icc < 2; ++icc) {
      #pragma unroll
      for (int k = 0; k < 9; ++k) {
        float4 v4 = *(const float4*)&s_v[icc][k * TPX + pg * 4];
        float4 wa = *(const float4*)&s_wd[icc][k][og * 8];
        float4 wb = *(const float4*)&s_wd[icc][k][og * 8 + 4];
        float vi[4] = {v4.x, v4.y, v4.z, v4.w};
        float wj[8] = {wa.x, wa.y, wa.z, wa.w, wb.x, wb.y, wb.z, wb.w};
        #pragma unroll
        for (int j = 0; j < 8; ++j)
          #pragma unroll
          for (int i = 0; i < 4; ++i)
            acc[j][i] = fmaf(wj[j], vi[i], acc[j][i]);
      }
    }
    __syncthreads();
  }
  #pragma unroll
  for (int j = 0; j < 8; ++j) {
    int oc = og * 8 + j;
    float4 o = make_float4(acc[j][0], acc[j][1], acc[j][2], acc[j][3]);
    *(float4*)&out[((size_t)(b * OC + oc)) * HW + p0 + pg * 4] = o;
  }
}

// ---------------- BN batch stats (biased var), one block per channel (fallback) ----------------
__global__ __launch_bounds__(256) void k_stats(
    const float* __restrict__ d, int perB, float* __restrict__ mean,
    float* __restrict__ rinv) {
  const int c = blockIdx.x, tid = threadIdx.x;
  double s1 = 0.0, s2 = 0.0;
  const int n4 = perB >> 2;
  for (int b = 0; b < BB; ++b) {
    const float4* p = (const float4*)(d + ((size_t)(b * CC + c)) * perB);
    for (int i = tid; i < n4; i += 256) {
      float4 v = p[i];
      s1 += (double)v.x + (double)v.y + (double)v.z + (double)v.w;
      s2 += (double)v.x * v.x + (double)v.y * v.y + (double)v.z * v.z + (double)v.w * v.w;
    }
  }
  __shared__ double r1[256], r2[256];
  r1[tid] = s1; r2[tid] = s2;
  __syncthreads();
  for (int s = 128; s > 0; s >>= 1) {
    if (tid < s) { r1[tid] += r1[tid + s]; r2[tid] += r2[tid + s]; }
    __syncthreads();
  }
  if (tid == 0) {
    double n = (double)perB * BB;
    double m = r1[0] / n;
    double var = r2[0] / n - m * m;
    mean[c] = (float)m;
    rinv[c] = (float)(1.0 / sqrt(var + (double)EPSV));
  }
}

// ---------------- BN stats, 2-level: partials per (b,c), then finalize ----------------
__global__ __launch_bounds__(256) void k_stats_part(
    const float* __restrict__ d, int perB, double* __restrict__ part) {
  const int c = blockIdx.x & 255, b = blockIdx.x >> 8;
  const int tid = threadIdx.x;
  double s1 = 0.0, s2 = 0.0;
  const float4* p = (const float4*)(d + ((size_t)(b * CC + c)) * perB);
  const int n4 = perB >> 2;
  for (int i = tid; i < n4; i += 256) {
    float4 v = p[i];
    s1 += (double)v.x + (double)v.y + (double)v.z + (double)v.w;
    s2 += (double)v.x * v.x + (double)v.y * v.y + (double)v.z * v.z + (double)v.w * v.w;
  }
  __shared__ double r1[256], r2[256];
  r1[tid] = s1; r2[tid] = s2;
  __syncthreads();
  for (int s = 128; s > 0; s >>= 1) {
    if (tid < s) { r1[tid] += r1[tid + s]; r2[tid] += r2[tid + s]; }
    __syncthreads();
  }
  if (tid == 0) {
    part[blockIdx.x] = r1[0];
    part[1024 + blockIdx.x] = r2[0];
  }
}

__global__ __launch_bounds__(256) void k_stats_fin(
    const double* __restrict__ part, int perB, float* __restrict__ mean,
    float* __restrict__ rinv) {
  const int c = threadIdx.x;  // 1 block x 256 threads
  double s1 = 0.0, s2 = 0.0;
  #pragma unroll
  for (int b = 0; b < BB; ++b) {
    s1 += part[b * 256 + c];
    s2 += part[1024 + b * 256 + c];
  }
  double n = (double)perB * BB;
  double m = s1 / n;
  double var = s2 / n - m * m;
  mean[c] = (float)m;
  rinv[c] = (float)(1.0 / sqrt(var + (double)EPSV));
}

// ---------------- BN apply + ReLU, in place ----------------
__global__ __launch_bounds__(256) void k_bnrelu(
    float* __restrict__ d, const float* __restrict__ mean,
    const float* __restrict__ rinv, const float* __restrict__ g,
    const float* __restrict__ be, int perB, int total4) {
  int stride = gridDim.x * blockDim.x;
  for (int i4 = blockIdx.x * blockDim.x + threadIdx.x; i4 < total4; i4 += stride) {
    int c = (int)((((long long)i4 * 4) / perB) & 255);
    float sc = rinv[c] * g[c];
    float shv = fmaf(-mean[c], sc, be[c]);
    float4 v = ((float4*)d)[i4];
    v.x = fmaxf(fmaf(v.x, sc, shv), 0.f);
    v.y = fmaxf(fmaf(v.y, sc, shv), 0.f);
    v.z = fmaxf(fmaf(v.z, sc, shv), 0.f);
    v.w = fmaxf(fmaf(v.w, sc, shv), 0.f);
    ((float4*)d)[i4] = v;
  }
}

// halo zeroing helper: block (h, cg, wg, b) zeroes its 32-ch slice of the 1-px halo
__device__ __forceinline__ void halo_zero(f16* __restrict__ dst, int b, int h,
                                          int cg, int wg, int t) {
  const f16x8 z = {};
  if (t < 4) {
    f16* p = dst + (((size_t)(b * 66 + h + 1) * 66) + (wg ? 65 : 0)) * 256 + cg * 32 + t * 8;
    *(f16x8*)p = z;
  }
  if (h == 0 || h == 63) {
    int hr = (h == 0) ? 0 : 65;
    if (t < 128) {
      int col = wg * 32 + 1 + (t >> 2);
      f16* p = dst + (((size_t)(b * 66 + hr) * 66) + col) * 256 + cg * 32 + (t & 3) * 8;
      *(f16x8*)p = z;
    }
    if (t >= 128 && t < 132) {
      f16* p = dst + (((size_t)(b * 66 + hr) * 66) + (wg ? 65 : 0)) * 256 + cg * 32 + (t - 128) * 8;
      *(f16x8*)p = z;
    }
  }
}

// ---------------- NCHW f32 -> padded NHWC f16 dst[b][66][66][256], halo zeroed ----------------
__global__ __launch_bounds__(256) void k_totile(const float* __restrict__ y,
                                                f16* __restrict__ yTp) {
  __shared__ float S[32][33];
  const int h = blockIdx.x;
  const int cg = blockIdx.y >> 1;
  const int wg = blockIdx.y & 1;
  const int b = blockIdx.z;
  const int t = threadIdx.x;
  {
    int ci = t >> 3, q = t & 7;
    const float* src = y + (((size_t)(b * 256 + cg * 32 + ci) * 64 + h) * 64 + wg * 32 + q * 4);
    float4 v = *(const float4*)src;
    S[ci][q * 4 + 0] = v.x; S[ci][q * 4 + 1] = v.y;
    S[ci][q * 4 + 2] = v.z; S[ci][q * 4 + 3] = v.w;
  }
  halo_zero(yTp, b, h, cg, wg, t);
  __syncthreads();
  {
    int w = t >> 3, c2 = t & 7;
    f16x4 pv;
    pv[0] = (f16)S[c2 * 4 + 0][w];
    pv[1] = (f16)S[c2 * 4 + 1][w];
    pv[2] = (f16)S[c2 * 4 + 2][w];
    pv[3] = (f16)S[c2 * 4 + 3][w];
    f16* dst = yTp + (((size_t)(b * 66 + h + 1) * 66 + (wg * 32 + w + 1)) * 256 + cg * 32 + c2 * 4);
    *(f16x4*)dst = pv;
  }
}

// ---------------- fused: BN+ReLU (in place on y) + padded NHWC f16 tile, halo zeroed --------
__global__ __launch_bounds__(256) void k_totile_bn(
    const float* __restrict__ mean, const float* __restrict__ rinv,
    const float* __restrict__ g, const float* __restrict__ be,
    float* __restrict__ y, f16* __restrict__ yTp) {
  __shared__ float S[32][33];
  const int h = blockIdx.x;
  const int cg = blockIdx.y >> 1;
  const int wg = blockIdx.y & 1;
  const int b = blockIdx.z;
  const int t = threadIdx.x;
  {
    int ci = t >> 3, q = t & 7;
    int c = cg * 32 + ci;
    float sc = rinv[c] * g[c];
    float sh = fmaf(-mean[c], sc, be[c]);
    float* src = y + (((size_t)(b * 256 + c) * 64 + h) * 64 + wg * 32 + q * 4);
    float4 v = *(const float4*)src;
    v.x = fmaxf(fmaf(v.x, sc, sh), 0.f);
    v.y = fmaxf(fmaf(v.y, sc, sh), 0.f);
    v.z = fmaxf(fmaf(v.z, sc, sh), 0.f);
    v.w = fmaxf(fmaf(v.w, sc, sh), 0.f);
    *(float4*)src = v;
    S[ci][q * 4 + 0] = v.x; S[ci][q * 4 + 1] = v.y;
    S[ci][q * 4 + 2] = v.z; S[ci][q * 4 + 3] = v.w;
  }
  halo_zero(yTp, b, h, cg, wg, t);
  __syncthreads();
  {
    int w = t >> 3, c2 = t & 7;
    f16x4 pv;
    pv[0] = (f16)S[c2 * 4 + 0][w];
    pv[1] = (f16)S[c2 * 4 + 1][w];
    pv[2] = (f16)S[c2 * 4 + 2][w];
    pv[3] = (f16)S[c2 * 4 + 3][w];
    f16* dst = yTp + (((size_t)(b * 66 + h + 1) * 66 + (wg * 32 + w + 1)) * 256 + cg * 32 + c2 * 4);
    *(f16x4*)dst = pv;
  }
}

// ---------------- merged weight prep: wprep(128) | wodprep(32) | wdprep(256) ----------------
__global__ __launch_bounds__(256) void k_prep(
    const float* __restrict__ wu, f16* __restrict__ Wt,
    const float* __restrict__ wo, f16* __restrict__ Wod,
    const float* __restrict__ wd, f16* __restrict__ Wd) {
  const int bx = blockIdx.x;
  if (bx < 128) {
    const int ic = bx * 2;
    const int oc = threadIdx.x;
    float a[16], c[16];
    const float* p0 = wu + ((size_t)(ic * 256 + oc)) * 16;
    const float* p1 = wu + ((size_t)((ic + 1) * 256 + oc)) * 16;
    #pragma unroll
    for (int k = 0; k < 4; ++k) {
      float4 v = *(const float4*)(p0 + k * 4);
      a[k * 4 + 0] = v.x; a[k * 4 + 1] = v.y; a[k * 4 + 2] = v.z; a[k * 4 + 3] = v.w;
      float4 w2 = *(const float4*)(p1 + k * 4);
      c[k * 4 + 0] = w2.x; c[k * 4 + 1] = w2.y; c[k * 4 + 2] = w2.z; c[k * 4 + 3] = w2.w;
    }
    #pragma unroll
    for (int kh = 0; kh < 4; ++kh)
      #pragma unroll
      for (int kw = 0; kw < 4; ++kw) {
        int po = (kh & 1) ^ 1, dh = kh >> 1;
        int qo = (kw & 1) ^ 1, dw = kw >> 1;
        int combo = (po * 2 + qo) * 4 + (dh * 2 + dw);
        f16x2 pv;
        pv[0] = (f16)a[kh * 4 + kw];
        pv[1] = (f16)c[kh * 4 + kw];
        *(f16x2*)&Wt[((size_t)(combo * 256 + oc)) * 256 + ic] = pv;
      }
  } else if (bx < 160) {
    const int oc = bx - 128;
    const int ic = threadIdx.x;
    const int icg = ic >> 3, e = ic & 7;
    #pragma unroll
    for (int tap = 0; tap < 9; ++tap) {
      f16 v = (f16)0.f;
      if (oc < NOFF) v = (f16)wo[((size_t)oc * 256 + ic) * 9 + tap];
      Wod[(((size_t)(tap * 32 + icg)) * 32 + oc) * 8 + e] = v;
    }
  } else {
    const int oc = bx - 160;
    const int ic = threadIdx.x;
    const float* src = wd + ((size_t)oc * 256 + ic) * 9;
    f16* dst = Wd + (((size_t)(ic >> 3) * 256 + oc)) * 8 + (ic & 7);
    #pragma unroll
    for (int tap = 0; tap < 9; ++tap)
      dst[(size_t)tap * 32 * 256 * 8] = (f16)src[tap];
  }
}

// standalone wprep for the fallback path
__global__ __launch_bounds__(256) void k_wprep(const float* __restrict__ wu,
                                               f16* __restrict__ Wt) {
  const int ic = blockIdx.x * 2;
  const int oc = threadIdx.x;
  float a[16], c[16];
  const float* p0 = wu + ((size_t)(ic * 256 + oc)) * 16;
  const float* p1 = wu + ((size_t)((ic + 1) * 256 + oc)) * 16;
  #pragma unroll
  for (int k = 0; k < 4; ++k) {
    float4 v = *(const float4*)(p0 + k * 4);
    a[k * 4 + 0] = v.x; a[k * 4 + 1] = v.y; a[k * 4 + 2] = v.z; a[k * 4 + 3] = v.w;
    float4 w2 = *(const float4*)(p1 + k * 4);
    c[k * 4 + 0] = w2.x; c[k * 4 + 1] = w2.y; c[k * 4 + 2] = w2.z; c[k * 4 + 3] = w2.w;
  }
  #pragma unroll
  for (int kh = 0; kh < 4; ++kh)
    #pragma unroll
    for (int kw = 0; kw < 4; ++kw) {
      int po = (kh & 1) ^ 1, dh = kh >> 1;
      int qo = (kw & 1) ^ 1, dw = kw >> 1;
      int combo = (po * 2 + qo) * 4 + (dh * 2 + dw);
      f16x2 pv;
      pv[0] = (f16)a[kh * 4 + kw];
      pv[1] = (f16)c[kh * 4 + kw];
      *(f16x2*)&Wt[((size_t)(combo * 256 + oc)) * 256 + ic] = pv;
    }
}

// ---------------- offset conv as MFMA GEMM, one image row per block ----------------
__global__ __launch_bounds__(256) void k_off_mfma(
    const f16* __restrict__ xtp, const f16* __restrict__ Wod,
    const float* __restrict__ bias, float* __restrict__ om) {
  __shared__ __align__(16) f16 Alds[9 * 4 * 32 * 8];  // 18 KB, slot = idx
  __shared__ __align__(16) f16 Blds[3 * 4 * 66 * 8];  // 12.4 KB, slot = idx
  const int b = blockIdx.y;
  const int r = blockIdx.x;            // image row 0..63
  const int tid = threadIdx.x;
  const int lane = tid & 63, wave = tid >> 6;
  const int l15 = lane & 15, l4 = lane >> 4;
  const int wbase = tid & 192;
  f32x4 acc[2] = {};
  const size_t xbase = ((size_t)b * 66 + r) * 66;  // padded rows r..r+2

  for (int ic0 = 0; ic0 < 256; ic0 += 32) {
    __syncthreads();
    #pragma unroll
    for (int i = 0; i < 5; ++i) {
      int idx = i * 256 + tid;
      if (idx < 1152) {
        int tap = idx >> 7, g = (idx >> 5) & 3, oc = idx & 31;
        const f16* gp = Wod + (((size_t)(tap * 32 + (ic0 >> 3) + g)) * 32 + oc) * 8;
        GLOAD16(gp, Alds + (size_t)(i * 256 + wbase) * 8);
      }
    }
    #pragma unroll
    for (int i = 0; i < 4; ++i) {
      int idx = i * 256 + tid;
      if (idx < 792) {
        int rp4g = idx / 66, c = idx - rp4g * 66;
        int rp = rp4g >> 2, g = rp4g & 3;
        const f16* gp = xtp + ((xbase + rp * 66 + c) * 256 + ic0 + g * 8);
        GLOAD16(gp, Blds + (size_t)(i * 256 + wbase) * 8);
      }
    }
    __syncthreads();
    #pragma unroll
    for (int tap = 0; tap < 9; ++tap) {
      const int ky = tap / 3, kx = tap % 3;
      f16x8 af[2];
      #pragma unroll
      for (int fi = 0; fi < 2; ++fi)
        af[fi] = *(const f16x8*)&Alds[((tap * 4 + l4) * 32 + fi * 16 + l15) * 8];
      f16x8 bf = *(const f16x8*)&Blds[((ky * 4 + l4) * 66 + wave * 16 + l15 + kx) * 8];
      #pragma unroll
      for (int fi = 0; fi < 2; ++fi)
        acc[fi] = __builtin_amdgcn_mfma_f32_16x16x32_f16(af[fi], bf, acc[fi], 0, 0, 0);
    }
  }
  #pragma unroll
  for (int fi = 0; fi < 2; ++fi) {
    #pragma unroll
    for (int r4 = 0; r4 < 4; ++r4) {
      int oc = fi * 16 + l4 * 4 + r4;
      if (oc < NOFF) {
        float v = acc[fi][r4] + bias[oc];
        if (oc >= 18) v = 1.f / (1.f + expf(-v));
        om[((size_t)(b * NOFF + oc)) * HW + r * 64 + wave * 16 + l15] = v;
      }
    }
  }
}

// ---------------- bilinear+mask sampling from padded xtp: V[vb][tap][icg][px][8] ----------------
__global__ __launch_bounds__(256) void k_sample(
    const f16* __restrict__ xtp, const float* __restrict__ om,
    f16* __restrict__ V, int b0) {
  const int tap = blockIdx.y;
  const int vb = blockIdx.z;
  const int b = b0 + vb;
  const int p = blockIdx.x * 64 + (threadIdx.x & 63);
  const int icg0 = threadIdx.x >> 6;
  const int h = p >> 6, w = p & 63;
  const float offx = om[((size_t)(b * NOFF + tap)) * HW + p];
  const float offy = om[((size_t)(b * NOFF + 9 + tap)) * HW + p];
  const float msk  = om[((size_t)(b * NOFF + 18 + tap)) * HW + p];
  float sy = offy + (float)(tap / 3 - 1) + (float)h;
  float sx = offx + (float)(tap % 3 - 1) + (float)w;
  float fy = floorf(sy), fx = floorf(sx);
  float ly = sy - fy, lx = sx - fx;
  int iy = (int)fy, ix = (int)fx;
  int idx[4];
  float wg[4];
  #pragma unroll
  for (int cnr = 0; cnr < 4; ++cnr) {
    int dy = cnr >> 1, dx = cnr & 1;
    int yy = iy + dy, xx = ix + dx;
    bool val = (yy >= 0) & (yy < HH) & (xx >= 0) & (xx < WW2);
    float wt = (dy ? ly : 1.f - ly) * (dx ? lx : 1.f - lx) * msk;
    idx[cnr] = val ? ((yy + 1) * 66 + (xx + 1)) : 0;
    wg[cnr] = val ? wt : 0.f;
  }
  const f16* xb = xtp + (size_t)b * 66 * 66 * 256;
  f16* vout = V + (((size_t)(vb * 9 + tap) * 32) * HW + p) * 8;
  #pragma unroll
  for (int it = 0; it < 8; ++it) {
    int icg = icg0 + it * 4;
    f16x8 c0 = *(const f16x8*)(xb + (size_t)idx[0] * 256 + icg * 8);
    f16x8 c1 = *(const f16x8*)(xb + (size_t)idx[1] * 256 + icg * 8);
    f16x8 c2 = *(const f16x8*)(xb + (size_t)idx[2] * 256 + icg * 8);
    f16x8 c3 = *(const f16x8*)(xb + (size_t)idx[3] * 256 + icg * 8);
    f16x8 r;
    #pragma unroll
    for (int e = 0; e < 8; ++e) {
      float s = wg[0] * (float)c0[e];
      s = fmaf(wg[1], (float)c1[e], s);
      s = fmaf(wg[2], (float)c2[e], s);
      s = fmaf(wg[3], (float)c3[e], s);
      r[e] = (f16)s;
    }
    *(f16x8*)(vout + (size_t)icg * HW * 8) = r;
  }
}

// ---------------- DCN GEMM via MFMA, 128oc x 64px tile, BK=64, global_load_lds ----------------
// grid (64 pxtile, 2 octile, nb), block 256 = 4 waves (2m x 2n; wave = 64oc x 32px)
__global__ __launch_bounds__(256) void k_dcn_mfma(
    const f16* __restrict__ V, const f16* __restrict__ Wd,
    float* __restrict__ out, int b0) {
  __shared__ __align__(16) f16 Alds[8 * 128 * 8];   // 16 KB, slot = idx (g*128+oc)
  __shared__ __align__(16) f16 Blds[8 * 64 * 8];    // 8 KB,  slot = idx (g*64+px)
  const int vb = blockIdx.z;
  const int b = b0 + vb;
  const int oc0 = blockIdx.y * 128;
  const int px0 = blockIdx.x * 64;
  const int tid = threadIdx.x;
  const int lane = tid & 63;
  const int wave = tid >> 6;
  const int wm = wave >> 1, wn = wave & 1;
  const int l15 = lane & 15, l4 = lane >> 4;
  const int wbase = tid & 192;  // wave*64
  f32x4 acc[4][2] = {};
  const size_t vrow = (size_t)(vb * 9) * 32;

  for (int tap = 0; tap < 9; ++tap) {
    for (int kk = 0; kk < 4; ++kk) {  // 64 ic per step
      __syncthreads();  // previous compute done before DMA overwrites LDS
      #pragma unroll
      for (int i = 0; i < 4; ++i) {   // A: 1024 chunks
        int idx = i * 256 + tid;
        int g = idx >> 7, q = idx & 127;
        const f16* gpA = Wd + (((size_t)((tap * 32 + kk * 8 + g) * 256) + oc0 + q)) * 8;
        GLOAD16(gpA, Alds + (size_t)(i * 256 + wbase) * 8);
      }
      #pragma unroll
      for (int i = 0; i < 2; ++i) {   // B: 512 chunks
        int idx = i * 256 + tid;
        int g = idx >> 6, q = idx & 63;
        const f16* gpB = V + ((vrow + tap * 32 + kk * 8 + g) * HW + px0 + q) * 8;
        GLOAD16(gpB, Blds + (size_t)(i * 256 + wbase) * 8);
      }
      __syncthreads();  // vmcnt(0) drain -> staged data visible
      #pragma unroll
      for (int half = 0; half < 2; ++half) {
        f16x8 af[4], bf[2];
        #pragma unroll
        for (int fi = 0; fi < 4; ++fi)
          af[fi] = *(const f16x8*)&Alds[(((half * 4 + l4) * 128) + wm * 64 + fi * 16 + l15) * 8];
        #pragma unroll
        for (int ni = 0; ni < 2; ++ni)
          bf[ni] = *(const f16x8*)&Blds[(((half * 4 + l4) * 64) + wn * 32 + ni * 16 + l15) * 8];
        #pragma unroll
        for (int fi = 0; fi < 4; ++fi)
          #pragma unroll
          for (int ni = 0; ni < 2; ++ni)
            acc[fi][ni] = __builtin_amdgcn_mfma_f32_16x16x32_f16(af[fi], bf[ni], acc[fi][ni], 0, 0, 0);
      }
    }
  }
  #pragma unroll
  for (int fi = 0; fi < 4; ++fi) {
    int oc = oc0 + wm * 64 + fi * 16 + l4 * 4;
    #pragma unroll
    for (int ni = 0; ni < 2; ++ni) {
      int px = px0 + wn * 32 + ni * 16 + l15;
      float* op = out + ((size_t)(b * OC + oc)) * HW + px;
      #pragma unroll
      for (int r = 0; r < 4; ++r)
        op[(size_t)r * HW] = acc[fi][ni][r];
    }
  }
}

// ---------------- ConvTranspose2d: 4 subpixel GEMMs, 128oc x 256px tile ----------------
// grid (16 sh-quads, 8 = sub*2+octile, 4 b), block 256 = 4 waves (2m x 2n, wave 64oc x 128px)
__global__ __launch_bounds__(256) void k_up_mfma(
    const f16* __restrict__ yTp, const f16* __restrict__ Wt,
    float* __restrict__ out) {
  __shared__ __align__(16) f16 Alds[4 * 4 * 128 * 8];  // 32 KB, slot (tap*4+g)*128+oc
  __shared__ __align__(16) f16 Blds[5 * 4 * 66 * 8];   // 20.6 KB, slot (rp*4+g)*66+c
  const int b = blockIdx.z;
  const int sub = blockIdx.y >> 1;
  const int po = sub >> 1, qo = sub & 1;
  const int oc0 = (blockIdx.y & 1) * 128;
  const int sh0 = blockIdx.x * 4;
  const int tid = threadIdx.x;
  const int lane = tid & 63, wave = tid >> 6;
  const int wm = wave >> 1, wn = wave & 1;
  const int l15 = lane & 15, l4 = lane >> 4;
  const int wbase = tid & 192;  // wave*64
  f32x4 acc[4][8] = {};
  const size_t yrow = ((size_t)b * 66 + (sh0 + po)) * 66;

  for (int ic0 = 0; ic0 < 256; ic0 += 32) {
    __syncthreads();  // previous compute done before DMA overwrites LDS
    // stage A: 2048 chunks (4 taps x 4 g x 128 oc)
    #pragma unroll
    for (int i = 0; i < 8; ++i) {
      int idx = i * 256 + tid;
      int tap = idx >> 9, g = (idx >> 7) & 3, oc = idx & 127;
      const f16* gp = Wt + (((size_t)((sub * 4 + tap) * 256 + oc0 + oc)) * 256 + ic0 + g * 8);
      GLOAD16(gp, Alds + (size_t)(i * 256 + wbase) * 8);
    }
    // stage B: 1320 chunks (5 rows x 4 g x 66 cols)
    #pragma unroll
    for (int i = 0; i < 6; ++i) {
      int idx = i * 256 + tid;
      if (idx < 1320) {
        int rp4g = idx / 66, c = idx - rp4g * 66;
        int rp = rp4g >> 2, g = rp4g & 3;
        const f16* gp = yTp + ((yrow + rp * 66 + c) * 256 + ic0 + g * 8);
        GLOAD16(gp, Blds + (size_t)(i * 256 + wbase) * 8);
      }
    }
    __syncthreads();  // vmcnt(0) drain -> staged data visible
    #pragma unroll
    for (int tap = 0; tap < 4; ++tap) {
      const int dh = tap >> 1, dw = tap & 1;
      f16x8 af[4];
      #pragma unroll
      for (int fi = 0; fi < 4; ++fi)
        af[fi] = *(const f16x8*)&Alds[((tap * 4 + l4) * 128 + wm * 64 + fi * 16 + l15) * 8];
      #pragma unroll
      for (int ni = 0; ni < 8; ++ni) {
        int px = wn * 128 + ni * 16 + l15;
        int prow = px >> 6;
        int cp = (px & 63) + qo - dw + 1;
        f16x8 bf = *(const f16x8*)&Blds[(((prow + 1 - dh) * 4 + l4) * 66 + cp) * 8];
        #pragma unroll
        for (int fi = 0; fi < 4; ++fi)
          acc[fi][ni] = __builtin_amdgcn_mfma_f32_16x16x32_f16(af[fi], bf, acc[fi][ni], 0, 0, 0);
      }
    }
  }
  #pragma unroll
  for (int fi = 0; fi < 4; ++fi) {
    int oc = oc0 + wm * 64 + fi * 16 + l4 * 4;
    #pragma unroll
    for (int ni = 0; ni < 8; ++ni) {
      int px = wn * 128 + ni * 16 + l15;
      int sh = sh0 + (px >> 6);
      int ow = 2 * (px & 63) + qo;
      float* op = out + ((size_t)(b * 256 + oc)) * UP_HW + (2 * sh + po) * 128 + ow;
      #pragma unroll
      for (int r = 0; r < 4; ++r)
        op[(size_t)r * UP_HW] = acc[fi][ni][r];
    }
  }
}

extern "C" void kernel_launch(void* const* d_in, const int* in_sizes, int n_in,
                              void* d_out, int out_size, void* d_ws, size_t ws_size,
                              hipStream_t stream) {
  const float* x      = (const float*)d_in[0];
  const float* w_off  = (const float*)d_in[1];
  const float* b_off  = (const float*)d_in[2];
  const float* w_dcn  = (const float*)d_in[3];
  const float* gamma1 = (const float*)d_in[4];
  const float* beta1  = (const float*)d_in[5];
  const float* w_up   = (const float*)d_in[6];
  const float* gamma2 = (const float*)d_in[7];
  const float* beta2  = (const float*)d_in[8];

  float* out1 = (float*)d_out;                   // y      [4,256,64,64]
  float* out2 = out1 + (size_t)BB * OC * HW;     // y_up   [4,256,128,128]

  char* wsb = (char*)d_ws;
  float* om    = (float*)wsb;                               // 1,769,472
  float* mean1 = (float*)(wsb + 1769472);
  float* rinv1 = mean1 + 256;
  float* mean2 = rinv1 + 256;
  float* rinv2 = mean2 + 256;
  f16* yTp = (f16*)(wsb + 1773568);                         // 8,921,088
  f16* Wt  = (f16*)(wsb + 10694656);                        // 2,097,152
  f16* xtp = (f16*)(wsb + 12791808);                        // 8,921,088
  f16* Wd  = (f16*)(wsb + 21712896);                        // 1,179,648
  f16* Wod = (f16*)(wsb + 22892544);                        // 147,456
  f16* V   = (f16*)(wsb + 23040000);                        // nb * 18,874,368
  const size_t FIXED_END = 23040000;
  const size_t VB_BYTES = 18874368;

  int nb = 0;
  if (ws_size >= FIXED_END + 4 * VB_BYTES) nb = 4;
  else if (ws_size >= FIXED_END + 2 * VB_BYTES) nb = 2;
  else if (ws_size >= FIXED_END + VB_BYTES) nb = 1;

  if (nb > 0) {
    double* partd = (double*)V;  // V space reused as 16 KB stats-partials scratch
    hipLaunchKernelGGL(k_prep, dim3(416), dim3(256), 0, stream, w_up, Wt, w_off, Wod, w_dcn, Wd);
    hipLaunchKernelGGL(k_totile, dim3(64, 16, BB), dim3(256), 0, stream, x, xtp);
    hipLaunchKernelGGL(k_off_mfma, dim3(64, BB), dim3(256), 0, stream, xtp, Wod, b_off, om);
    for (int b0 = 0; b0 < BB; b0 += nb) {
      hipLaunchKernelGGL(k_sample, dim3(64, 9, nb), dim3(256), 0, stream, xtp, om, V, b0);
      hipLaunchKernelGGL(k_dcn_mfma, dim3(64, 2, nb), dim3(256), 0, stream, V, Wd, out1, b0);
    }
    hipLaunchKernelGGL(k_stats_part, dim3(1024), dim3(256), 0, stream, out1, HW, partd);
    hipLaunchKernelGGL(k_stats_fin, dim3(1), dim3(256), 0, stream, partd, HW, mean1, rinv1);
    hipLaunchKernelGGL(k_totile_bn, dim3(64, 16, BB), dim3(256), 0, stream,
                       mean1, rinv1, gamma1, beta1, out1, yTp);
    hipLaunchKernelGGL(k_up_mfma, dim3(16, 8, BB), dim3(256), 0, stream, yTp, Wt, out2);
    hipLaunchKernelGGL(k_stats_part, dim3(1024), dim3(256), 0, stream, out2, UP_HW, partd);
    hipLaunchKernelGGL(k_stats_fin, dim3(1), dim3(256), 0, stream, partd, UP_HW, mean2, rinv2);
  } else {
    hipLaunchKernelGGL(k_wprep, dim3(128), dim3(256), 0, stream, w_up, Wt);
    hipLaunchKernelGGL(k_offset, dim3(16, 9, BB), dim3(256), 0, stream, x, w_off, b_off, om);
    hipLaunchKernelGGL(k_dcn, dim3(HW / TPX, BB), dim3(256), 0, stream, x, om, w_dcn, out1);
    hipLaunchKernelGGL(k_stats, dim3(256), dim3(256), 0, stream, out1, HW, mean1, rinv1);
    hipLaunchKernelGGL(k_bnrelu, dim3(2048), dim3(256), 0, stream, out1, mean1, rinv1,
                       gamma1, beta1, HW, (BB * OC * HW) / 4);
    hipLaunchKernelGGL(k_totile, dim3(64, 16, BB), dim3(256), 0, stream, out1, yTp);
    hipLaunchKernelGGL(k_up_mfma, dim3(16, 8, BB), dim3(256), 0, stream, yTp, Wt, out2);
    hipLaunchKernelGGL(k_stats, dim3(256), dim3(256), 0, stream, out2, UP_HW, mean2, rinv2);
  }

  hipLaunchKernelGGL(k_bnrelu, dim3(2048), dim3(256), 0, stream, out2, mean2, rinv2,
                     gamma2, beta2, UP_HW, (BB * OC * UP_HW) / 4);
}